// Round 5
// baseline (40.869 us; speedup 1.0000x reference)
//
#include <hip/hip_runtime.h>
#include <math.h>

// ---- problem constants ----
#define NCH   2048
#define SZ    14
#define NPOS  (SZ*SZ)        // 196
#define NQ    (NPOS/4)       // 49 float4 per channel plane
#define BLK_CH 64            // channels per k1 block
#define SPB   (NCH/BLK_CH)   // 32 slices (blocks) per batch
#define TACT  245            // 5*49 active threads in k1
#define NWIN  917
#define NB    64
#define PN    7
#define KPER  6              // ceil(361/64) strided candidates per lane

// window tables (13 ratios)
__device__ const int g_rh[13]    = {4,3,5,6,5,7,8,6,10,7,9,7,10};
__device__ const int g_rw[13]    = {4,5,3,6,7,5,8,10,6,10,7,10,7};
__device__ const int g_wbase[14] = {0,121,241,361,442,522,602,651,696,741,789,837,877,917};
// NOTE: g_rw above must match reference; fixed literal below in ctor check.

// -------- kernel 1: DIAGNOSTIC 2x-read channel-sum (structure == round 4) --
// Reads the identical address stream twice with a compiler memory barrier
// between passes (prevents CSE), accumulates both, stores *0.5f.
// Purpose: double k1's duration so it surfaces in the top-5 rocprof rows
// with its own hbm_gbps/FETCH_SIZE/VALUBusy/Occupancy, and give a clean
// total-time differential vs round 4.
__global__ __launch_bounds__(256) void k_chansum(const float4* __restrict__ x,
                                                 float4* __restrict__ part) {
  const int b   = blockIdx.x;
  const int blk = blockIdx.y;
  const int t   = threadIdx.x;

  __shared__ float4 red[5][49];

  if (t < TACT) {
    const size_t base = ((size_t)b * NCH + (size_t)blk * BLK_CH) * NQ;
    float ax = 0.f, ay = 0.f, az = 0.f, aw = 0.f;
    // ---- pass 1 ----
#pragma unroll
    for (int i = 0; i < 12; ++i) {
      const float4 v = x[base + i * TACT + t];
      ax += v.x; ay += v.y; az += v.z; aw += v.w;
    }
    if (t < 196) {
      const float4 v = x[base + 2940 + t];
      ax += v.x; ay += v.y; az += v.z; aw += v.w;
    }
    asm volatile("" ::: "memory");   // forbid CSE of the second pass
    // ---- pass 2 (identical addresses) ----
#pragma unroll
    for (int i = 0; i < 12; ++i) {
      const float4 v = x[base + i * TACT + t];
      ax += v.x; ay += v.y; az += v.z; aw += v.w;
    }
    if (t < 196) {
      const float4 v = x[base + 2940 + t];
      ax += v.x; ay += v.y; az += v.z; aw += v.w;
    }
    float4 o; o.x = ax * 0.5f; o.y = ay * 0.5f; o.z = az * 0.5f; o.w = aw * 0.5f;
    red[t / 49][t % 49] = o;
  }
  __syncthreads();

  if (t < 49) {
    const float4 r0 = red[0][t], r1 = red[1][t], r2 = red[2][t],
                 r3 = red[3][t], r4 = red[4][t];
    float4 o;
    o.x = r0.x + r1.x + r2.x + r3.x + r4.x;
    o.y = r0.y + r1.y + r2.y + r3.y + r4.y;
    o.z = r0.z + r1.z + r2.z + r3.z + r4.z;
    o.w = r0.w + r1.w + r2.w + r3.w + r4.w;
    part[((size_t)b * SPB + blk) * NQ + t] = o;
  }
}

// -------- kernel 2: windows + wave-parallel NMS (identical to round 4) ----
__global__ __launch_bounds__(256) void k_nms(const float* __restrict__ part,
                                             float* __restrict__ out) {
  const int b    = blockIdx.x;
  const int tid  = threadIdx.x;
  const int lane = tid & 63;
  const int wave = tid >> 6;

  __shared__ float s[NPOS];
  __shared__ float sc[NWIN];
  __shared__ float bx1[NWIN], by1[NWIN], bx2[NWIN], by2[NWIN], bar[NWIN];

  // correct ratio tables (local, compile-time)
  const int rh[13] = {4,3,5,6,5,7,8,6,10,7,9,7,10};
  const int rw[13] = {4,5,3,6,7,5,8,10,6,9,7,10,7};
  const int wb[14] = {0,121,241,361,442,522,602,651,696,741,789,837,877,917};

  if (tid < NPOS) {
    float acc = 0.f;
    const float* p = part + (size_t)b * SPB * NPOS + tid;
#pragma unroll 8
    for (int sl = 0; sl < SPB; ++sl) acc += p[sl * NPOS];
    s[tid] = acc;
  }
  __syncthreads();

  for (int w = tid; w < NWIN; w += 256) {
    int r = 0;
    while (w >= wb[r + 1]) ++r;
    const int l  = w - wb[r];
    const int RH = rh[r], RW = rw[r];
    const int ww = SZ - RW + 1;
    const int xi = l / ww, yi = l % ww;
    float sum = 0.f;
    for (int i = 0; i < RH; ++i)
      for (int j = 0; j < RW; ++j)
        sum += s[(xi + i) * SZ + (yi + j)];
    const float score = sum / (float)(RH * RW);
    sc[w] = score;
    out[NB * PN * 2 + b * NWIN + w] = score;
    float x1 = (float)(xi * 32 - 1);
    float y1 = (float)(yi * 32 - 1);
    float x2 = x1 + (float)(RH * 32);
    float y2 = y1 + (float)(RW * 32);
    if (x1 < 0.f) x1 = 0.f;
    if (y1 < 0.f) y1 = 0.f;
    bx1[w] = x1; by1[w] = y1; bx2[w] = x2; by2[w] = y2;
    bar[w] = (x2 - x1 + 1.f) * (y2 - y1 + 1.f);
  }
  __syncthreads();

  if (wave < 3) {
    const int glo[3] = {0, 361, 602};
    const int ghi[3] = {361, 602, 917};
    const int gns[3] = {2, 3, 2};
    const int gob[3] = {0, 2, 5};
    const int lo = glo[wave], hi = ghi[wave];
    const int nsel = gns[wave], obase = gob[wave];

    float wk[KPER], X1[KPER], Y1[KPER], X2[KPER], Y2[KPER], AR[KPER];
#pragma unroll
    for (int k = 0; k < KPER; ++k) {
      const int j = lo + lane + k * 64;
      const bool v = j < hi;
      const int jj = v ? j : lo;
      wk[k] = v ? sc[jj] : -INFINITY;
      X1[k] = bx1[jj]; Y1[k] = by1[jj];
      X2[k] = bx2[jj]; Y2[k] = by2[jj]; AR[k] = bar[jj];
    }

    for (int st = 0; st < nsel; ++st) {
      float bv = -INFINITY; int bj = 0x7fffffff;
#pragma unroll
      for (int k = 0; k < KPER; ++k) {
        const int j = lo + lane + k * 64;
        if (wk[k] > bv) { bv = wk[k]; bj = j; }   // strict > keeps smallest j
      }
      for (int off = 32; off > 0; off >>= 1) {
        const float ov = __shfl_xor(bv, off);
        const int   oj = __shfl_xor(bj, off);
        if (ov > bv || (ov == bv && oj < bj)) { bv = ov; bj = oj; }
      }
      const float sx1 = bx1[bj], sy1 = by1[bj];
      const float sx2 = bx2[bj], sy2 = by2[bj], sar = bar[bj];
      if (lane == 0) {
        out[b * PN + obase + st]           = (float)bj;
        out[NB * PN + b * PN + obase + st] = sc[bj];
      }
#pragma unroll
      for (int k = 0; k < KPER; ++k) {
        const int j = lo + lane + k * 64;
        const float ix1 = fmaxf(X1[k], sx1);
        const float iy1 = fmaxf(Y1[k], sy1);
        const float ix2 = fminf(X2[k], sx2);
        const float iy2 = fminf(Y2[k], sy2);
        const float lw = ix2 - ix1 + 1.f;
        const float lh = iy2 - iy1 + 1.f;
        const float inter = (lw < 0.f || lh < 0.f) ? 0.f : lw * lh;
        const float iou = inter / (AR[k] + sar - inter);
        if (iou > 0.25f || j == bj) wk[k] = -INFINITY;
      }
    }
  }
}

extern "C" void kernel_launch(void* const* d_in, const int* in_sizes, int n_in,
                              void* d_out, int out_size, void* d_ws, size_t ws_size,
                              hipStream_t stream) {
  const float4* x = (const float4*)d_in[0];
  float* out = (float*)d_out;
  float4* part = (float4*)d_ws;   // 64*32*49 float4 = 1.6 MB

  dim3 g1(NB, SPB);
  k_chansum<<<g1, 256, 0, stream>>>(x, part);
  k_nms<<<NB, 256, 0, stream>>>((const float*)d_ws, out);
}

// Round 6
// 33.552 us; speedup vs baseline: 1.2181x; 1.2181x over previous
//
#include <hip/hip_runtime.h>
#include <math.h>

// ---- problem constants ----
#define NCH    2048
#define SZ     14
#define NPOS   (SZ*SZ)         // 196
#define NQ     (NPOS/4)        // 49 float4 per channel plane
#define F4B    (NCH*NQ)        // 100352 float4 per batch
#define TACT   980             // 20*49 active threads
#define NITER  102             // 102*980 = 99960
#define TAILN  392             // 100352-99960 = 392 = 8*49
#define NWIN   917
#define NB     64
#define PN     7
#define KPER   6               // ceil(361/64) strided candidates per lane

// One block per batch: stream 1.6 MB -> s[196] -> 917 window scores -> NMS.
// 64 blocks x 1024 threads (16 waves). Thread t < 980 reads float4 index
// base + i*980 + t; 980 % 49 == 0 keeps its plane position t%49 constant,
// so accumulation stays in registers and every load iteration is a fully
// dense, coalesced 15.7 KB block read with deep ILP.
__global__ __launch_bounds__(1024) void k_appm(const float4* __restrict__ x,
                                               float* __restrict__ out) {
  const int b    = blockIdx.x;
  const int tid  = threadIdx.x;
  const int lane = tid & 63;
  const int wave = tid >> 6;

  __shared__ float4 red[20][NQ];     // 15.7 KB
  __shared__ float  s[NPOS];
  __shared__ float  sc[NWIN];
  __shared__ float  bx1[NWIN], by1[NWIN], bx2[NWIN], by2[NWIN], bar[NWIN];

  // window tables
  const int rh[13] = {4,3,5,6,5,7,8,6,10,7,9,7,10};
  const int rw[13] = {4,5,3,6,7,5,8,10,6,9,7,10,7};
  const int wb[14] = {0,121,241,361,442,522,602,651,696,741,789,837,877,917};

  // ---- phase 1: stream the batch's 2048x196 floats ----
  if (tid < TACT) {
    const size_t base = (size_t)b * F4B;
    float ax = 0.f, ay = 0.f, az = 0.f, aw = 0.f;
#pragma unroll 17
    for (int i = 0; i < NITER; ++i) {
      const float4 v = x[base + (size_t)i * TACT + tid];
      ax += v.x; ay += v.y; az += v.z; aw += v.w;
    }
    if (tid < TAILN) {                 // tail 392 = 8*49; 99960 % 49 == 0
      const float4 v = x[base + 99960 + tid];
      ax += v.x; ay += v.y; az += v.z; aw += v.w;
    }
    float4 o; o.x = ax; o.y = ay; o.z = az; o.w = aw;
    red[tid / NQ][tid % NQ] = o;
  }
  __syncthreads();

  // ---- 20-way reduce -> s[196] ----
  if (tid < NQ) {
    float ax = 0.f, ay = 0.f, az = 0.f, aw = 0.f;
#pragma unroll
    for (int r = 0; r < 20; ++r) {
      const float4 v = red[r][tid];
      ax += v.x; ay += v.y; az += v.z; aw += v.w;
    }
    s[tid * 4 + 0] = ax; s[tid * 4 + 1] = ay;
    s[tid * 4 + 2] = az; s[tid * 4 + 3] = aw;
  }
  __syncthreads();

  // ---- window scores + coords (clamp AFTER x2/y2, exactly as reference) ----
  if (tid < NWIN) {
    const int w = tid;
    int r = 0;
    while (w >= wb[r + 1]) ++r;
    const int l  = w - wb[r];
    const int RH = rh[r], RW = rw[r];
    const int ww = SZ - RW + 1;
    const int xi = l / ww, yi = l % ww;
    float sum = 0.f;
    for (int i = 0; i < RH; ++i)
      for (int j = 0; j < RW; ++j)
        sum += s[(xi + i) * SZ + (yi + j)];
    const float score = sum / (float)(RH * RW);
    sc[w] = score;
    out[NB * PN * 2 + b * NWIN + w] = score;
    float x1 = (float)(xi * 32 - 1);
    float y1 = (float)(yi * 32 - 1);
    float x2 = x1 + (float)(RH * 32);
    float y2 = y1 + (float)(RW * 32);
    if (x1 < 0.f) x1 = 0.f;
    if (y1 < 0.f) y1 = 0.f;
    bx1[w] = x1; by1[w] = y1; bx2[w] = x2; by2[w] = y2;
    bar[w] = (x2 - x1 + 1.f) * (y2 - y1 + 1.f);
  }
  __syncthreads();

  // ---- wave-parallel greedy NMS: wave g owns group g ----
  if (wave < 3) {
    const int glo[3] = {0, 361, 602};
    const int ghi[3] = {361, 602, 917};
    const int gns[3] = {2, 3, 2};
    const int gob[3] = {0, 2, 5};
    const int lo = glo[wave], hi = ghi[wave];
    const int nsel = gns[wave], obase = gob[wave];

    float wk[KPER], X1[KPER], Y1[KPER], X2[KPER], Y2[KPER], AR[KPER];
#pragma unroll
    for (int k = 0; k < KPER; ++k) {
      const int j = lo + lane + k * 64;
      const bool v = j < hi;
      const int jj = v ? j : lo;
      wk[k] = v ? sc[jj] : -INFINITY;
      X1[k] = bx1[jj]; Y1[k] = by1[jj];
      X2[k] = bx2[jj]; Y2[k] = by2[jj]; AR[k] = bar[jj];
    }

    for (int st = 0; st < nsel; ++st) {
      float bv = -INFINITY; int bj = 0x7fffffff;
#pragma unroll
      for (int k = 0; k < KPER; ++k) {
        const int j = lo + lane + k * 64;
        if (wk[k] > bv) { bv = wk[k]; bj = j; }   // strict > keeps smallest j
      }
      for (int off = 32; off > 0; off >>= 1) {
        const float ov = __shfl_xor(bv, off);
        const int   oj = __shfl_xor(bj, off);
        if (ov > bv || (ov == bv && oj < bj)) { bv = ov; bj = oj; }
      }
      // bj uniform across the wave
      const float sx1 = bx1[bj], sy1 = by1[bj];
      const float sx2 = bx2[bj], sy2 = by2[bj], sar = bar[bj];
      if (lane == 0) {
        out[b * PN + obase + st]           = (float)bj;
        out[NB * PN + b * PN + obase + st] = sc[bj];
      }
#pragma unroll
      for (int k = 0; k < KPER; ++k) {
        const int j = lo + lane + k * 64;
        const float ix1 = fmaxf(X1[k], sx1);
        const float iy1 = fmaxf(Y1[k], sy1);
        const float ix2 = fminf(X2[k], sx2);
        const float iy2 = fminf(Y2[k], sy2);
        const float lw = ix2 - ix1 + 1.f;
        const float lh = iy2 - iy1 + 1.f;
        const float inter = (lw < 0.f || lh < 0.f) ? 0.f : lw * lh;
        const float iou = inter / (AR[k] + sar - inter);
        if (iou > 0.25f || j == bj) wk[k] = -INFINITY;
      }
    }
  }
}

extern "C" void kernel_launch(void* const* d_in, const int* in_sizes, int n_in,
                              void* d_out, int out_size, void* d_ws, size_t ws_size,
                              hipStream_t stream) {
  const float4* x = (const float4*)d_in[0];
  float* out = (float*)d_out;
  k_appm<<<NB, 1024, 0, stream>>>(x, out);
}